// Round 25
// baseline (2020.164 us; speedup 1.0000x reference)
//
#include <hip/hip_runtime.h>

// R25: PURE kc=512 CANDIDATE (R23 exact-fit decode: absmax 0.59375 = bf16
// of 303/512 = the theoretical-max pattern for golden==kc512, achieved at a
// boundary site where all five other candidates straddled).
//   dot (K=4096): 8 panels of kc=512; within panel single-accumulator FMA
//                 chain (k ascending); one rounded add per panel boundary
//                 (OpenBLAS sgemm per-element semantics, Zen Q=512).
//   bias:         separately-rounded f32 add
//   inner (k=3):  FMA chain + separately-rounded blif add  (confirmed by
//                 R23's absence of all-six-wrong sites)
//   recurrence:   strict separately-rounded f32 (numpy ufuncs), pre-update
//                 inner (confirmed R22)
//   output:       binary spikes as f32, ((b*wins+t)*C+c)*4+d layout
//                 (geometry validated R17/R21-R23).

constexpr int Bsz = 256;
constexpr int C   = 4096;
constexpr int K   = 4096;
constexpr int KC  = 512;

__global__ void lif_r25(
    const float* __restrict__ x,
    const float* __restrict__ W1, const float* __restrict__ b1,
    const float* __restrict__ W2, const float* __restrict__ b2,
    const float* __restrict__ W3, const float* __restrict__ b3,
    const float* __restrict__ Wlif, const float* __restrict__ blif,
    float* __restrict__ out, int wins)
{
    const int c = blockIdx.x;      // 0..4095  (channel)
    const int b = threadIdx.x;     // 0..255   (batch)

    const float* __restrict__ xr  = x  + (size_t)b * K;
    const float* __restrict__ w1r = W1 + (size_t)c * K;
    const float* __restrict__ w2r = W2 + (size_t)c * K;
    const float* __restrict__ w3r = W3 + (size_t)c * K;

    // --- kc=512-blocked dots: FMA chain within panel, rounded add per panel ---
    float a0 = 0.0f, a1 = 0.0f, a2 = 0.0f;
    for (int p = 0; p < K; p += KC) {
        float c0 = 0.0f, c1 = 0.0f, c2 = 0.0f;
        for (int k = p; k < p + KC; k += 4) {
            const float4 xv  = *reinterpret_cast<const float4*>(&xr[k]);
            const float4 w1v = *reinterpret_cast<const float4*>(&w1r[k]);
            const float4 w2v = *reinterpret_cast<const float4*>(&w2r[k]);
            const float4 w3v = *reinterpret_cast<const float4*>(&w3r[k]);
            c0 = fmaf(xv.x, w1v.x, c0); c0 = fmaf(xv.y, w1v.y, c0);
            c0 = fmaf(xv.z, w1v.z, c0); c0 = fmaf(xv.w, w1v.w, c0);
            c1 = fmaf(xv.x, w2v.x, c1); c1 = fmaf(xv.y, w2v.y, c1);
            c1 = fmaf(xv.z, w2v.z, c1); c1 = fmaf(xv.w, w2v.w, c1);
            c2 = fmaf(xv.x, w3v.x, c2); c2 = fmaf(xv.y, w3v.y, c2);
            c2 = fmaf(xv.z, w3v.z, c2); c2 = fmaf(xv.w, w3v.w, c2);
        }
        if (p == 0) { a0 = c0; a1 = c1; a2 = c2; }       // beta=0 first panel
        else {
            a0 = __fadd_rn(a0, c0);
            a1 = __fadd_rn(a1, c1);
            a2 = __fadd_rn(a2, c2);
        }
    }

    const float x0 = __fadd_rn(a0, b1[c]);
    const float x1 = __fadd_rn(a1, b2[c]);
    const float x2 = __fadd_rn(a2, b3[c]);

    const float w0 = Wlif[0], w1 = Wlif[1], w2 = Wlif[2], bl = blif[0];

    float mm0 = 0.0f, mm1 = 0.0f, mm2 = 0.0f, mm3 = 0.0f;
    float s0 = 0.0f, s1 = 0.0f, s2 = 0.0f, s3 = 0.0f;

    for (int t = 0; t < wins; ++t) {
        // inner = mem[0:3]@Wlif.T (FMA chain) + blif (rounded add), carry mem
        const float ia = fmaf(mm2, w2, fmaf(mm1, w1, fmaf(mm0, w0, 0.0f)));
        const float inner = __fadd_rn(ia, bl);

        // mem1 = ((mem * 0.2) * (1 - spike)) + input  (each op rounded sep.)
        const float g0 = __fsub_rn(1.0f, s0);
        const float g1 = __fsub_rn(1.0f, s1);
        const float g2 = __fsub_rn(1.0f, s2);
        const float g3 = __fsub_rn(1.0f, s3);
        mm0 = __fadd_rn(__fmul_rn(__fmul_rn(mm0, 0.2f), g0), x0);
        mm1 = __fadd_rn(__fmul_rn(__fmul_rn(mm1, 0.2f), g1), x1);
        mm2 = __fadd_rn(__fmul_rn(__fmul_rn(mm2, 0.2f), g2), x2);
        mm3 = __fadd_rn(__fmul_rn(__fmul_rn(mm3, 0.2f), g3), inner);

        s0 = (mm0 > 0.8f) ? 1.0f : 0.0f;
        s1 = (mm1 > 0.8f) ? 1.0f : 0.0f;
        s2 = (mm2 > 0.8f) ? 1.0f : 0.0f;
        s3 = (mm3 > 0.8f) ? 1.0f : 0.0f;

        const size_t base = (((size_t)b * wins + t) * C + c) * 4;
        float4 sp; sp.x = s0; sp.y = s1; sp.z = s2; sp.w = s3;
        *reinterpret_cast<float4*>(&out[base]) = sp;
    }
}

extern "C" void kernel_launch(void* const* d_in, const int* in_sizes, int n_in,
                              void* d_out, int out_size, void* d_ws, size_t ws_size,
                              hipStream_t stream) {
    const float* x    = (const float*)d_in[0];
    const float* W1   = (const float*)d_in[1];
    const float* b1   = (const float*)d_in[2];
    const float* W2   = (const float*)d_in[3];
    const float* b2   = (const float*)d_in[4];
    const float* W3   = (const float*)d_in[5];
    const float* b3   = (const float*)d_in[6];
    const float* Wlif = (const float*)d_in[7];
    const float* blif = (const float*)d_in[8];

    const int wins = out_size / (Bsz * C * 4);   // 15

    lif_r25<<<dim3(C), dim3(Bsz), 0, stream>>>(
        x, W1, b1, W2, b2, W3, b3, Wlif, blif,
        (float*)d_out, wins);
}

// Round 26
// 463.274 us; speedup vs baseline: 4.3606x; 4.3606x over previous
//
#include <hip/hip_runtime.h>

// R26: OPTIMIZED fused GEMM+LIF, exact R25 semantics (validated absmax=0.0):
//   dot: kc=512 panels, per-element single-accumulator FMA chain k-ascending,
//        __fadd_rn fold per panel boundary; FMA-chain inner + rounded blif;
//        strict separately-rounded f32 recurrence; f32 binary spike output.
// Structure: LDS-tiled. Block = 64(b) x 32(c) tile, BK=16, 256 threads,
// 4x2 microtile x 3 matrices (24 panel + 24 total accumulators).
// R25 was latency-bound (VALUBusy 13.5%, HBM 6%): uncoalesced per-lane x
// reads + scattered stores. This version stages tiles via LDS (coalesced),
// gives each thread 24 independent chains (ILP), and stores 32B-contiguous
// per thread (coalesced spike writes).

constexpr int Bsz = 256;
constexpr int C   = 4096;
constexpr int K   = 4096;
constexpr int KC  = 512;

constexpr int BM = 64;    // batch tile
constexpr int BN = 32;    // channel tile
constexpr int BK = 16;    // k step

__global__ __launch_bounds__(256) void lif_r26(
    const float* __restrict__ x,
    const float* __restrict__ W1, const float* __restrict__ b1,
    const float* __restrict__ W2, const float* __restrict__ b2,
    const float* __restrict__ W3, const float* __restrict__ b3,
    const float* __restrict__ Wlif, const float* __restrict__ blif,
    float* __restrict__ out, int wins)
{
    __shared__ float As [BK][BM + 4];   // x tile,  [k][b]
    __shared__ float Bs1[BK][BN + 4];   // W1 tile, [k][c]
    __shared__ float Bs2[BK][BN + 4];
    __shared__ float Bs3[BK][BN + 4];

    const int bn = blockIdx.x * BN;     // channel base
    const int bm = blockIdx.y * BM;     // batch base

    const int tid = threadIdx.x;
    const int tx = tid & 15;            // c micro: 2 channels (tx*2, tx*2+1)
    const int ty = tid >> 4;            // b micro: 4 batches  (ty*4 .. +3)

    // staging assignments (coalesced global loads)
    const int xlr = tid >> 2;           // 0..63 : x tile row
    const int xlc = (tid & 3) * 4;      // 0,4,8,12 : k offset (float4)
    const int wlr = tid >> 3;           // 0..31 : W tile row
    const int wlc = (tid & 7) * 2;      // 0,2,..,14 : k offset (float2)

    float pan[3][4][2];                 // panel accumulators [j][bi][cj]
    float tot[3][4][2];                 // panel totals
#pragma unroll
    for (int j = 0; j < 3; ++j)
#pragma unroll
        for (int i = 0; i < 4; ++i)
#pragma unroll
            for (int jj = 0; jj < 2; ++jj) { pan[j][i][jj] = 0.f; tot[j][i][jj] = 0.f; }

    for (int k0 = 0; k0 < K; k0 += BK) {
        const float4 xa  = *reinterpret_cast<const float4*>(&x [(size_t)(bm + xlr) * K + k0 + xlc]);
        const float2 w1a = *reinterpret_cast<const float2*>(&W1[(size_t)(bn + wlr) * K + k0 + wlc]);
        const float2 w2a = *reinterpret_cast<const float2*>(&W2[(size_t)(bn + wlr) * K + k0 + wlc]);
        const float2 w3a = *reinterpret_cast<const float2*>(&W3[(size_t)(bn + wlr) * K + k0 + wlc]);

        __syncthreads();                 // previous tile fully consumed
        As [xlc + 0][xlr] = xa.x;  As [xlc + 1][xlr] = xa.y;
        As [xlc + 2][xlr] = xa.z;  As [xlc + 3][xlr] = xa.w;
        Bs1[wlc + 0][wlr] = w1a.x; Bs1[wlc + 1][wlr] = w1a.y;
        Bs2[wlc + 0][wlr] = w2a.x; Bs2[wlc + 1][wlr] = w2a.y;
        Bs3[wlc + 0][wlr] = w3a.x; Bs3[wlc + 1][wlr] = w3a.y;
        __syncthreads();

#pragma unroll
        for (int kk = 0; kk < BK; ++kk) {
            const float4 av  = *reinterpret_cast<const float4*>(&As [kk][ty * 4]);
            const float2 b1v = *reinterpret_cast<const float2*>(&Bs1[kk][tx * 2]);
            const float2 b2v = *reinterpret_cast<const float2*>(&Bs2[kk][tx * 2]);
            const float2 b3v = *reinterpret_cast<const float2*>(&Bs3[kk][tx * 2]);
            const float a[4]     = { av.x, av.y, av.z, av.w };
            const float bw[3][2] = { { b1v.x, b1v.y }, { b2v.x, b2v.y }, { b3v.x, b3v.y } };
#pragma unroll
            for (int j = 0; j < 3; ++j)
#pragma unroll
                for (int i = 0; i < 4; ++i)
#pragma unroll
                    for (int jj = 0; jj < 2; ++jj)
                        pan[j][i][jj] = fmaf(a[i], bw[j][jj], pan[j][i][jj]);
        }

        // kc=512 panel boundary: one rounded add per element, reset panel
        if (((k0 + BK) & (KC - 1)) == 0) {
#pragma unroll
            for (int j = 0; j < 3; ++j)
#pragma unroll
                for (int i = 0; i < 4; ++i)
#pragma unroll
                    for (int jj = 0; jj < 2; ++jj) {
                        tot[j][i][jj] = __fadd_rn(tot[j][i][jj], pan[j][i][jj]);
                        pan[j][i][jj] = 0.f;
                    }
        }
    }

    // ---- epilogue: bias + LIF recurrence + coalesced spike stores ----
    const float w0 = Wlif[0], w1 = Wlif[1], w2 = Wlif[2], bl = blif[0];

#pragma unroll
    for (int i = 0; i < 4; ++i) {
        const int b = bm + ty * 4 + i;
        const int c0 = bn + tx * 2;

        // per-element x3 (bias separately rounded)
        float X[2][3];
#pragma unroll
        for (int jj = 0; jj < 2; ++jj) {
            X[jj][0] = __fadd_rn(tot[0][i][jj], b1[c0 + jj]);
            X[jj][1] = __fadd_rn(tot[1][i][jj], b2[c0 + jj]);
            X[jj][2] = __fadd_rn(tot[2][i][jj], b3[c0 + jj]);
        }

        float mmA0 = 0.f, mmA1 = 0.f, mmA2 = 0.f, mmA3 = 0.f;   // jj = 0
        float sA0 = 0.f, sA1 = 0.f, sA2 = 0.f, sA3 = 0.f;
        float mmB0 = 0.f, mmB1 = 0.f, mmB2 = 0.f, mmB3 = 0.f;   // jj = 1
        float sB0 = 0.f, sB1 = 0.f, sB2 = 0.f, sB3 = 0.f;

        for (int t = 0; t < wins; ++t) {
            // inner: FMA chain + rounded blif add (carry mem)
            const float iaA = fmaf(mmA2, w2, fmaf(mmA1, w1, fmaf(mmA0, w0, 0.0f)));
            const float innerA = __fadd_rn(iaA, bl);
            const float iaB = fmaf(mmB2, w2, fmaf(mmB1, w1, fmaf(mmB0, w0, 0.0f)));
            const float innerB = __fadd_rn(iaB, bl);

            mmA0 = __fadd_rn(__fmul_rn(__fmul_rn(mmA0, 0.2f), __fsub_rn(1.f, sA0)), X[0][0]);
            mmA1 = __fadd_rn(__fmul_rn(__fmul_rn(mmA1, 0.2f), __fsub_rn(1.f, sA1)), X[0][1]);
            mmA2 = __fadd_rn(__fmul_rn(__fmul_rn(mmA2, 0.2f), __fsub_rn(1.f, sA2)), X[0][2]);
            mmA3 = __fadd_rn(__fmul_rn(__fmul_rn(mmA3, 0.2f), __fsub_rn(1.f, sA3)), innerA);
            mmB0 = __fadd_rn(__fmul_rn(__fmul_rn(mmB0, 0.2f), __fsub_rn(1.f, sB0)), X[1][0]);
            mmB1 = __fadd_rn(__fmul_rn(__fmul_rn(mmB1, 0.2f), __fsub_rn(1.f, sB1)), X[1][1]);
            mmB2 = __fadd_rn(__fmul_rn(__fmul_rn(mmB2, 0.2f), __fsub_rn(1.f, sB2)), X[1][2]);
            mmB3 = __fadd_rn(__fmul_rn(__fmul_rn(mmB3, 0.2f), __fsub_rn(1.f, sB3)), innerB);

            sA0 = (mmA0 > 0.8f) ? 1.f : 0.f;  sA1 = (mmA1 > 0.8f) ? 1.f : 0.f;
            sA2 = (mmA2 > 0.8f) ? 1.f : 0.f;  sA3 = (mmA3 > 0.8f) ? 1.f : 0.f;
            sB0 = (mmB0 > 0.8f) ? 1.f : 0.f;  sB1 = (mmB1 > 0.8f) ? 1.f : 0.f;
            sB2 = (mmB2 > 0.8f) ? 1.f : 0.f;  sB3 = (mmB3 > 0.8f) ? 1.f : 0.f;

            // two adjacent float4 stores = 32 B contiguous per thread,
            // coalesced across tx (adjacent threads cover adjacent c pairs)
            const size_t base = (((size_t)b * wins + t) * C + c0) * 4;
            float4 spA; spA.x = sA0; spA.y = sA1; spA.z = sA2; spA.w = sA3;
            float4 spB; spB.x = sB0; spB.y = sB1; spB.z = sB2; spB.w = sB3;
            *reinterpret_cast<float4*>(&out[base])     = spA;
            *reinterpret_cast<float4*>(&out[base + 4]) = spB;
        }
    }
}

extern "C" void kernel_launch(void* const* d_in, const int* in_sizes, int n_in,
                              void* d_out, int out_size, void* d_ws, size_t ws_size,
                              hipStream_t stream) {
    const float* x    = (const float*)d_in[0];
    const float* W1   = (const float*)d_in[1];
    const float* b1   = (const float*)d_in[2];
    const float* W2   = (const float*)d_in[3];
    const float* b2   = (const float*)d_in[4];
    const float* W3   = (const float*)d_in[5];
    const float* b3   = (const float*)d_in[6];
    const float* Wlif = (const float*)d_in[7];
    const float* blif = (const float*)d_in[8];

    const int wins = out_size / (Bsz * C * 4);   // 15

    dim3 grid(C / BN, Bsz / BM);                 // (128, 4) = 512 blocks
    lif_r26<<<grid, 256, 0, stream>>>(
        x, W1, b1, W2, b2, W3, b3, Wlif, blif,
        (float*)d_out, wins);
}